// Round 5
// baseline (1108.181 us; speedup 1.0000x reference)
//
#include <hip/hip_runtime.h>
#include <hip/hip_bf16.h>

#define N_NODES 102400
#define FEAT    400
#define F1      256
#define E_EDGES 4096000
#define NUM_G   256
#define NPG     400

typedef __attribute__((ext_vector_type(8))) short bfrag;   // 8 bf16 (4 VGPR)
typedef __attribute__((ext_vector_type(4))) float ffrag;   // 4 fp32 acc

__device__ inline short f2b(float f) {
    __hip_bfloat16 h = __float2bfloat16(f);
    return *reinterpret_cast<short*>(&h);
}
__device__ inline float b2f(short s) {
    unsigned int u = ((unsigned int)(unsigned short)s) << 16;
    return __builtin_bit_cast(float, u);
}

// ---------------- degree count + per-edge rank ----------------
__global__ __launch_bounds__(256) void k_count(const int* __restrict__ ei,
                                               int* __restrict__ cnt,
                                               int* __restrict__ rank) {
    int e = blockIdx.x * 256 + threadIdx.x;
    int d = ei[E_EDGES + e];
    rank[e] = atomicAdd(&cnt[d], 1);
}

__global__ __launch_bounds__(256) void k_dis(const int* __restrict__ cnt,
                                             float* __restrict__ dis) {
    int i = blockIdx.x * 256 + threadIdx.x;
    dis[i] = rsqrtf((float)(cnt[i] + 1));   // +1 self-loop; always > 0
}

// ---------------- prefix sum (3-phase) ----------------
__global__ __launch_bounds__(1024) void k_scan1(const int* __restrict__ cnt,
                                                int* __restrict__ part,
                                                int* __restrict__ bsum) {
    __shared__ int s[1024];
    int t = threadIdx.x, b = blockIdx.x;
    int gid = b * 1024 + t;
    s[t] = cnt[gid];
    __syncthreads();
    for (int off = 1; off < 1024; off <<= 1) {
        int v = (t >= off) ? s[t - off] : 0;
        __syncthreads();
        s[t] += v;
        __syncthreads();
    }
    part[gid] = s[t];            // inclusive
    if (t == 1023) bsum[b] = s[t];
}

__global__ void k_scan2(int* __restrict__ bsum) {
    if (threadIdx.x == 0) {
        int run = 0;
        for (int i = 0; i < N_NODES / 1024; ++i) {
            int v = bsum[i]; bsum[i] = run; run += v;
        }
    }
}

__global__ __launch_bounds__(1024) void k_scan3(const int* __restrict__ cnt,
                                                const int* __restrict__ part,
                                                const int* __restrict__ bsum,
                                                int* __restrict__ row_start) {
    int t = threadIdx.x, b = blockIdx.x;
    int gid = b * 1024 + t;
    int inc = part[gid];
    int ex = inc - cnt[gid] + bsum[b];      // exclusive
    row_start[gid] = ex;
    if (gid == N_NODES - 1) row_start[N_NODES] = inc + bsum[b];
}

// ---------------- CSR fill (no atomics; NT scatter store) ----------------
__global__ __launch_bounds__(256) void k_fill(const int* __restrict__ ei,
                                              const int* __restrict__ rank,
                                              const int* __restrict__ row_start,
                                              int* __restrict__ csr) {
    int e = blockIdx.x * 256 + threadIdx.x;
    int s = ei[e];
    int d = ei[E_EDGES + e];
    __builtin_nontemporal_store(s, &csr[row_start[d] + rank[e]]);
}

// ---------------- weight transpose+pad to bf16: Wt[256][Kpad] from W[Kreal][256] ----------------
__global__ __launch_bounds__(256) void k_cvt_w(const float* __restrict__ W,
                                               short* __restrict__ Wt,
                                               int Kreal, int Kpad) {
    int idx = blockIdx.x * 256 + threadIdx.x;
    if (idx >= 256 * Kpad) return;
    int n = idx / Kpad, k = idx - n * Kpad;
    float v = (k < Kreal) ? W[(size_t)k * 256 + n] : 0.f;
    Wt[idx] = f2b(v);
}

// ---------------- bf16 MFMA GEMM: C[M x 256](bf16) = A[M x K] @ Wt^T ----------------
// 128x128 tile, BK=32, 256 thr = 4 waves (2x2), 64x64 per wave = 4x4 frags 16x16x32
template<bool AF32>
__global__ __launch_bounds__(256) void k_mm(const void* __restrict__ Ap,
                                            const short* __restrict__ Wt, // [256][Kpad] bf16
                                            int Kreal, int Kpad,
                                            short* __restrict__ C) {     // [M][256] bf16
    __shared__ short As[128][40];   // rows m, cols k (pad 40 -> 80B stride, 16B aligned)
    __shared__ short Bs[128][40];   // rows n, cols k
    const int t    = threadIdx.x;
    const int lane = t & 63;
    const int w    = t >> 6;
    const int wm   = w >> 1, wn = w & 1;
    const int m0   = blockIdx.x * 128;
    const int n0   = blockIdx.y * 128;

    const int sr = t >> 1;           // staged row 0..127
    const int sh = (t & 1) * 16;     // k-half 0 / 16

    ffrag acc[4][4];
#pragma unroll
    for (int i = 0; i < 4; ++i)
#pragma unroll
        for (int j = 0; j < 4; ++j) {
            ffrag z = {0.f, 0.f, 0.f, 0.f};
            acc[i][j] = z;
        }

    const int rl = lane & 15;
    const int kc = (lane >> 4) * 8;

    for (int k0 = 0; k0 < Kpad; k0 += 32) {
        short av[16], bv[16];
        if constexpr (AF32) {
            const float* A = (const float*)Ap;
            const float* arow = A + (size_t)(m0 + sr) * Kreal + k0 + sh;
#pragma unroll
            for (int c = 0; c < 4; ++c) {
                float4 v;
                if (k0 + sh + c * 4 < Kreal) v = *(const float4*)(arow + c * 4);
                else                         v = make_float4(0.f, 0.f, 0.f, 0.f);
                av[c * 4 + 0] = f2b(v.x);
                av[c * 4 + 1] = f2b(v.y);
                av[c * 4 + 2] = f2b(v.z);
                av[c * 4 + 3] = f2b(v.w);
            }
        } else {
            const short* A = (const short*)Ap;
            const short* arow = A + (size_t)(m0 + sr) * Kpad + k0 + sh;
            *(bfrag*)&av[0] = *(const bfrag*)arow;
            *(bfrag*)&av[8] = *(const bfrag*)(arow + 8);
        }
        const short* brow = Wt + (size_t)(n0 + sr) * Kpad + k0 + sh;
        *(bfrag*)&bv[0] = *(const bfrag*)brow;
        *(bfrag*)&bv[8] = *(const bfrag*)(brow + 8);

        __syncthreads();
        *(bfrag*)&As[sr][sh]     = *(bfrag*)&av[0];
        *(bfrag*)&As[sr][sh + 8] = *(bfrag*)&av[8];
        *(bfrag*)&Bs[sr][sh]     = *(bfrag*)&bv[0];
        *(bfrag*)&Bs[sr][sh + 8] = *(bfrag*)&bv[8];
        __syncthreads();

        bfrag a[4], b[4];
#pragma unroll
        for (int i = 0; i < 4; ++i) a[i] = *(const bfrag*)&As[wm * 64 + i * 16 + rl][kc];
#pragma unroll
        for (int j = 0; j < 4; ++j) b[j] = *(const bfrag*)&Bs[wn * 64 + j * 16 + rl][kc];
#pragma unroll
        for (int i = 0; i < 4; ++i)
#pragma unroll
            for (int j = 0; j < 4; ++j)
                acc[i][j] = __builtin_amdgcn_mfma_f32_16x16x32_bf16(a[i], b[j], acc[i][j], 0, 0, 0);
    }

    const int rh = lane >> 4;
#pragma unroll
    for (int i = 0; i < 4; ++i)
#pragma unroll
        for (int j = 0; j < 4; ++j) {
            int col  = n0 + wn * 64 + j * 16 + rl;
            int rowb = m0 + wm * 64 + i * 16 + rh * 4;
#pragma unroll
            for (int q = 0; q < 4; ++q)
                C[(size_t)(rowb + q) * 256 + col] = f2b(acc[i][j][q]);
        }
}

// ---------------- normalized gather-aggregation over bf16 rows ----------------
// block = 128 thr per dst node; slot = t>>5 (edge j%4), fg = t&31 (features fg*8..+7)
// each thread loads 16B (bf16x8) per edge; 8 edges per inner iteration in flight
__global__ __launch_bounds__(128) void k_agg(const short* __restrict__ h,
                                             const float* __restrict__ dis,
                                             const int* __restrict__ row_start,
                                             const int* __restrict__ csr,
                                             const float* __restrict__ bias,
                                             void* __restrict__ outp, int layer1) {
    const int i    = blockIdx.x;
    const int t    = threadIdx.x;
    const int slot = t >> 5;
    const int fg   = t & 31;
    __shared__ int   s_src[128];
    __shared__ float s_nrm[128];
    __shared__ float s_red[32][10];   // pad 10 -> 2-way max (free)

    float di = dis[i];
    float acc[8] = {0.f, 0.f, 0.f, 0.f, 0.f, 0.f, 0.f, 0.f};
    if (slot == 0) {
        bfrag v = *(const bfrag*)(h + (size_t)i * 256 + fg * 8);
        float w = di * di;
#pragma unroll
        for (int k = 0; k < 8; ++k) acc[k] = b2f(v[k]) * w;
    }

    int beg = row_start[i], end = row_start[i + 1];
    for (int base = beg; base < end; base += 128) {
        int m = min(128, end - base);
        __syncthreads();
        if (t < m) {
            int s = csr[base + t];
            s_src[t] = s;
            s_nrm[t] = dis[s] * di;
        }
        __syncthreads();
        for (int j = 0; j < m; j += 8) {
            int j0 = j + slot, j1 = j + 4 + slot;
            bool ok0 = j0 < m, ok1 = j1 < m;
            int   s0 = s_src[ok0 ? j0 : 0];
            int   s1 = s_src[ok1 ? j1 : 0];
            float w0 = ok0 ? s_nrm[j0] : 0.f;
            float w1 = ok1 ? s_nrm[j1] : 0.f;
            bfrag v0 = *(const bfrag*)(h + (size_t)s0 * 256 + fg * 8);
            bfrag v1 = *(const bfrag*)(h + (size_t)s1 * 256 + fg * 8);
#pragma unroll
            for (int k = 0; k < 8; ++k) acc[k] = fmaf(b2f(v0[k]), w0, acc[k]);
#pragma unroll
            for (int k = 0; k < 8; ++k) acc[k] = fmaf(b2f(v1[k]), w1, acc[k]);
        }
    }

    // slot pairs within each wave (lane ^ 32)
#pragma unroll
    for (int k = 0; k < 8; ++k) acc[k] += __shfl_xor(acc[k], 32, 64);
    // wave1 (slots 2,3) -> LDS
    if (t >= 64 && t < 96) {
#pragma unroll
        for (int k = 0; k < 8; ++k) s_red[fg][k] = acc[k];
    }
    __syncthreads();
    if (t < 32) {
        const float* bp = bias + fg * 8;
        float r[8];
#pragma unroll
        for (int k = 0; k < 8; ++k) r[k] = acc[k] + s_red[fg][k] + bp[k];
        if (layer1) {
            short o[8];
#pragma unroll
            for (int k = 0; k < 8; ++k) o[k] = f2b(fmaxf(r[k], 0.f));
            *(bfrag*)((short*)outp + (size_t)i * 256 + fg * 8) = *(bfrag*)o;
        } else {
            float* op = (float*)outp + (size_t)i * 256 + fg * 8;
            *(float4*)op       = make_float4(r[0], r[1], r[2], r[3]);
            *(float4*)(op + 4) = make_float4(r[4], r[5], r[6], r[7]);
        }
    }
}

// ---------------- mean|max readout + final linear (4 chunks/graph, atomic partials) ----------------
__global__ __launch_bounds__(256) void k_readout(const float* __restrict__ h2,
                                                 const float* __restrict__ Wm,
                                                 const float* __restrict__ bm,
                                                 float* __restrict__ out) {
    int g = blockIdx.x, c = blockIdx.y;     // c: feature chunk 0..3
    int t = threadIdx.x;
    int fl = t & 63;                        // feature-in-chunk
    int f  = c * 64 + fl;
    int rs = t >> 6;                        // row subset 0..3 (one per wave)
    const float* base = h2 + (size_t)g * NPG * 256 + f;
    float sum = 0.f, mx = -3.402823466e38f;
    for (int r = rs; r < NPG; r += 4) {
        float v = base[(size_t)r * 256];
        sum += v;
        mx = fmaxf(mx, v);
    }
    __shared__ float s_sum[4][64];
    __shared__ float s_max[4][64];
    s_sum[rs][fl] = sum;
    s_max[rs][fl] = mx;
    __syncthreads();
    if (t < 64) {
        float ts = s_sum[0][t] + s_sum[1][t] + s_sum[2][t] + s_sum[3][t];
        float tm = fmaxf(fmaxf(s_max[0][t], s_max[1][t]), fmaxf(s_max[2][t], s_max[3][t]));
        float mean = ts * (1.0f / NPG);
        float p0 = mean * Wm[f * 2 + 0] + tm * Wm[(256 + f) * 2 + 0];
        float p1 = mean * Wm[f * 2 + 1] + tm * Wm[(256 + f) * 2 + 1];
        for (int o = 32; o > 0; o >>= 1) {
            p0 += __shfl_down(p0, o, 64);
            p1 += __shfl_down(p1, o, 64);
        }
        if (t == 0) {
            if (c == 0) { p0 += bm[0]; p1 += bm[1]; }
            atomicAdd(&out[g * 2 + 0], p0);
            atomicAdd(&out[g * 2 + 1], p1);
        }
    }
}

extern "C" void kernel_launch(void* const* d_in, const int* in_sizes, int n_in,
                              void* d_out, int out_size, void* d_ws, size_t ws_size,
                              hipStream_t stream) {
    const float* x  = (const float*)d_in[0];
    const int*   ei = (const int*)d_in[1];   // int64 in reference -> int32 on device
    // d_in[2] = batch (unused: batch = node/400), d_in[3] = num_graphs (unused)
    const float* W1 = (const float*)d_in[4];
    const float* b1 = (const float*)d_in[5];
    const float* W2 = (const float*)d_in[6];
    const float* b2 = (const float*)d_in[7];
    const float* Wm = (const float*)d_in[8];
    const float* bm = (const float*)d_in[9];
    float* out = (float*)d_out;

    char* ws = (char*)d_ws;
    size_t off = 0;
    auto alloc = [&](size_t bytes) {
        void* p = ws + off;
        off = (off + bytes + 255) & ~(size_t)255;
        return p;
    };
    int*   cnt       = (int*)alloc((size_t)N_NODES * 4);
    int*   part      = (int*)alloc((size_t)N_NODES * 4);
    int*   bsum      = (int*)alloc(512);
    int*   row_start = (int*)alloc((size_t)(N_NODES + 1) * 4);
    float* dis       = (float*)alloc((size_t)N_NODES * 4);
    int*   rank      = (int*)alloc((size_t)E_EDGES * 4);
    int*   csr       = (int*)alloc((size_t)E_EDGES * 4);
    short* Wt1       = (short*)alloc((size_t)256 * 416 * 2);
    short* Wt2       = (short*)alloc((size_t)256 * 256 * 2);
    short* Pb1       = (short*)alloc((size_t)N_NODES * F1 * 2);   // bf16 ping (gemm out)
    float* Pf        = (float*)alloc((size_t)N_NODES * F1 * 4);   // fp32 final; first half doubles as Pb2
    short* Pb2       = (short*)Pf;                                // bf16 pong (agg1 out), dead before agg2 writes Pf

    hipMemsetAsync(cnt, 0, (size_t)N_NODES * 4, stream);
    hipMemsetAsync(out, 0, (size_t)NUM_G * 2 * 4, stream);
    k_count<<<E_EDGES / 256, 256, 0, stream>>>(ei, cnt, rank);
    k_dis<<<N_NODES / 256, 256, 0, stream>>>(cnt, dis);
    k_scan1<<<N_NODES / 1024, 1024, 0, stream>>>(cnt, part, bsum);
    k_scan2<<<1, 64, 0, stream>>>(bsum);
    k_scan3<<<N_NODES / 1024, 1024, 0, stream>>>(cnt, part, bsum, row_start);
    k_fill<<<E_EDGES / 256, 256, 0, stream>>>(ei, rank, row_start, csr);

    k_cvt_w<<<(256 * 416 + 255) / 256, 256, 0, stream>>>(W1, Wt1, 400, 416);
    k_cvt_w<<<(256 * 256 + 255) / 256, 256, 0, stream>>>(W2, Wt2, 256, 256);

    dim3 gg(N_NODES / 128, 2);
    k_mm<true><<<gg, 256, 0, stream>>>((const void*)x, Wt1, 400, 416, Pb1);    // bf16(x@W1)
    k_agg<<<N_NODES, 128, 0, stream>>>(Pb1, dis, row_start, csr, b1,
                                       (void*)Pb2, 1);                         // relu(Agg+b1) -> bf16
    k_mm<false><<<gg, 256, 0, stream>>>((const void*)Pb2, Wt2, 256, 256, Pb1); // bf16(h1@W2)
    k_agg<<<N_NODES, 128, 0, stream>>>(Pb1, dis, row_start, csr, b2,
                                       (void*)Pf, 0);                          // Agg+b2 -> fp32
    k_readout<<<dim3(NUM_G, 4), 256, 0, stream>>>(Pf, Wm, bm, out);
}

// Round 6
// 910.210 us; speedup vs baseline: 1.2175x; 1.2175x over previous
//
#include <hip/hip_runtime.h>
#include <hip/hip_bf16.h>

#define N_NODES 102400
#define FEAT    400
#define F1      256
#define E_EDGES 4096000
#define NUM_G   256
#define NPG     400

typedef __attribute__((ext_vector_type(8))) short bfrag;   // 8 bf16 (4 VGPR)
typedef __attribute__((ext_vector_type(4))) float ffrag;   // 4 fp32 acc
typedef __attribute__((ext_vector_type(4))) short s4;      // 4 bf16 (8B)

__device__ inline short f2b(float f) {
    __hip_bfloat16 h = __float2bfloat16(f);
    return *reinterpret_cast<short*>(&h);
}
__device__ inline float b2f(short s) {
    unsigned int u = ((unsigned int)(unsigned short)s) << 16;
    return __builtin_bit_cast(float, u);
}

// ---------------- degree count + per-edge rank ----------------
__global__ __launch_bounds__(256) void k_count(const int* __restrict__ ei,
                                               int* __restrict__ cnt,
                                               int* __restrict__ rank) {
    int e = blockIdx.x * 256 + threadIdx.x;
    int d = ei[E_EDGES + e];
    rank[e] = atomicAdd(&cnt[d], 1);
}

__global__ __launch_bounds__(256) void k_dis(const int* __restrict__ cnt,
                                             float* __restrict__ dis) {
    int i = blockIdx.x * 256 + threadIdx.x;
    dis[i] = rsqrtf((float)(cnt[i] + 1));   // +1 self-loop; always > 0
}

// ---------------- prefix sum (3-phase) ----------------
__global__ __launch_bounds__(1024) void k_scan1(const int* __restrict__ cnt,
                                                int* __restrict__ part,
                                                int* __restrict__ bsum) {
    __shared__ int s[1024];
    int t = threadIdx.x, b = blockIdx.x;
    int gid = b * 1024 + t;
    s[t] = cnt[gid];
    __syncthreads();
    for (int off = 1; off < 1024; off <<= 1) {
        int v = (t >= off) ? s[t - off] : 0;
        __syncthreads();
        s[t] += v;
        __syncthreads();
    }
    part[gid] = s[t];            // inclusive
    if (t == 1023) bsum[b] = s[t];
}

__global__ void k_scan2(int* __restrict__ bsum) {
    if (threadIdx.x == 0) {
        int run = 0;
        for (int i = 0; i < N_NODES / 1024; ++i) {
            int v = bsum[i]; bsum[i] = run; run += v;
        }
    }
}

__global__ __launch_bounds__(1024) void k_scan3(const int* __restrict__ cnt,
                                                const int* __restrict__ part,
                                                const int* __restrict__ bsum,
                                                int* __restrict__ row_start) {
    int t = threadIdx.x, b = blockIdx.x;
    int gid = b * 1024 + t;
    int inc = part[gid];
    int ex = inc - cnt[gid] + bsum[b];      // exclusive
    row_start[gid] = ex;
    if (gid == N_NODES - 1) row_start[N_NODES] = inc + bsum[b];
}

// ---------------- CSR fill (no atomics: rank precomputed; plain store) ----------------
__global__ __launch_bounds__(256) void k_fill(const int* __restrict__ ei,
                                              const int* __restrict__ rank,
                                              const int* __restrict__ row_start,
                                              int* __restrict__ csr) {
    int e = blockIdx.x * 256 + threadIdx.x;
    int s = ei[e];
    int d = ei[E_EDGES + e];
    csr[row_start[d] + rank[e]] = s;
}

// ---------------- weight transpose+pad to bf16: Wt[256][Kpad] from W[Kreal][256] ----------------
__global__ __launch_bounds__(256) void k_cvt_w(const float* __restrict__ W,
                                               short* __restrict__ Wt,
                                               int Kreal, int Kpad) {
    int idx = blockIdx.x * 256 + threadIdx.x;
    if (idx >= 256 * Kpad) return;
    int n = idx / Kpad, k = idx - n * Kpad;
    float v = (k < Kreal) ? W[(size_t)k * 256 + n] : 0.f;
    Wt[idx] = f2b(v);
}

// ---------------- bf16 MFMA GEMM: C[M x 256] = (A[M x K] @ Wt^T) * dis[row] ----------------
// 128x128 tile, BK=32, 256 thr = 4 waves (2x2), 64x64 per wave = 4x4 frags 16x16x32
// OMODE 1: fp8 e4m3 output (prefolded). OMODE 2: bf16 output (prefolded).
template<bool AF32, int OMODE>
__global__ __launch_bounds__(256) void k_mm(const void* __restrict__ Ap,
                                            const short* __restrict__ Wt, // [256][Kpad] bf16
                                            const float* __restrict__ dis,
                                            int Kreal, int Kpad,
                                            void* __restrict__ Cp) {
    __shared__ short As[128][40];   // rows m, cols k (pad 40 -> 80B stride, 16B aligned)
    __shared__ short Bs[128][40];   // rows n, cols k
    const int t    = threadIdx.x;
    const int lane = t & 63;
    const int w    = t >> 6;
    const int wm   = w >> 1, wn = w & 1;
    const int m0   = blockIdx.x * 128;
    const int n0   = blockIdx.y * 128;

    const int sr = t >> 1;           // staged row 0..127
    const int sh = (t & 1) * 16;     // k-half 0 / 16

    ffrag acc[4][4];
#pragma unroll
    for (int i = 0; i < 4; ++i)
#pragma unroll
        for (int j = 0; j < 4; ++j) {
            ffrag z = {0.f, 0.f, 0.f, 0.f};
            acc[i][j] = z;
        }

    const int rl = lane & 15;
    const int kc = (lane >> 4) * 8;

    for (int k0 = 0; k0 < Kpad; k0 += 32) {
        short av[16], bv[16];
        if constexpr (AF32) {
            const float* A = (const float*)Ap;
            const float* arow = A + (size_t)(m0 + sr) * Kreal + k0 + sh;
#pragma unroll
            for (int c = 0; c < 4; ++c) {
                float4 v;
                if (k0 + sh + c * 4 < Kreal) v = *(const float4*)(arow + c * 4);
                else                         v = make_float4(0.f, 0.f, 0.f, 0.f);
                av[c * 4 + 0] = f2b(v.x);
                av[c * 4 + 1] = f2b(v.y);
                av[c * 4 + 2] = f2b(v.z);
                av[c * 4 + 3] = f2b(v.w);
            }
        } else {
            const short* A = (const short*)Ap;
            const short* arow = A + (size_t)(m0 + sr) * Kpad + k0 + sh;
            *(bfrag*)&av[0] = *(const bfrag*)arow;
            *(bfrag*)&av[8] = *(const bfrag*)(arow + 8);
        }
        const short* brow = Wt + (size_t)(n0 + sr) * Kpad + k0 + sh;
        *(bfrag*)&bv[0] = *(const bfrag*)brow;
        *(bfrag*)&bv[8] = *(const bfrag*)(brow + 8);

        __syncthreads();
        *(bfrag*)&As[sr][sh]     = *(bfrag*)&av[0];
        *(bfrag*)&As[sr][sh + 8] = *(bfrag*)&av[8];
        *(bfrag*)&Bs[sr][sh]     = *(bfrag*)&bv[0];
        *(bfrag*)&Bs[sr][sh + 8] = *(bfrag*)&bv[8];
        __syncthreads();

        bfrag a[4], b[4];
#pragma unroll
        for (int i = 0; i < 4; ++i) a[i] = *(const bfrag*)&As[wm * 64 + i * 16 + rl][kc];
#pragma unroll
        for (int j = 0; j < 4; ++j) b[j] = *(const bfrag*)&Bs[wn * 64 + j * 16 + rl][kc];
#pragma unroll
        for (int i = 0; i < 4; ++i)
#pragma unroll
            for (int j = 0; j < 4; ++j)
                acc[i][j] = __builtin_amdgcn_mfma_f32_16x16x32_bf16(a[i], b[j], acc[i][j], 0, 0, 0);
    }

    const int rh = lane >> 4;
    float scale[4][4];
#pragma unroll
    for (int i = 0; i < 4; ++i)
#pragma unroll
        for (int q = 0; q < 4; ++q)
            scale[i][q] = dis[m0 + wm * 64 + i * 16 + rh * 4 + q];

#pragma unroll
    for (int i = 0; i < 4; ++i)
#pragma unroll
        for (int j = 0; j < 4; ++j) {
            int col  = n0 + wn * 64 + j * 16 + rl;
            int rowb = m0 + wm * 64 + i * 16 + rh * 4;
#pragma unroll
            for (int q = 0; q < 4; ++q) {
                float v = acc[i][j][q] * scale[i][q];
                if constexpr (OMODE == 1) {
                    int p = __builtin_amdgcn_cvt_pk_fp8_f32(v, 0.f, 0, false);
                    ((unsigned char*)Cp)[(size_t)(rowb + q) * 256 + col] = (unsigned char)(p & 0xff);
                } else {
                    ((short*)Cp)[(size_t)(rowb + q) * 256 + col] = f2b(v);
                }
            }
        }
}

// ---------------- layer-1 aggregation over fp8 prefolded rows ----------------
// 64 thr/block = 1 wave per dst node; lane t holds features 4t..4t+3 (one dword of fp8)
// out = bf16( relu( di * (self + sum_s stored[s]) + b1 ) )
__global__ __launch_bounds__(64) void k_agg8(const unsigned int* __restrict__ h8, // [N][64] dwords
                                             const float* __restrict__ dis,
                                             const int* __restrict__ row_start,
                                             const int* __restrict__ csr,
                                             const float* __restrict__ bias,
                                             short* __restrict__ out) {
    const int i = blockIdx.x;
    const int t = threadIdx.x;
    __shared__ int s_src[64];
    float di = dis[i];
    unsigned int u = h8[(size_t)i * 64 + t];
    auto lo = __builtin_amdgcn_cvt_pk_f32_fp8(u, false);
    auto hi = __builtin_amdgcn_cvt_pk_f32_fp8(u, true);
    float a0 = lo[0], a1 = lo[1], a2 = hi[0], a3 = hi[1];

    int beg = row_start[i], end = row_start[i + 1];
    for (int base = beg; base < end; base += 64) {
        int m = min(64, end - base);
        __syncthreads();
        if (t < m) s_src[t] = csr[base + t];
        __syncthreads();
        for (int j = 0; j < m; ++j) {
            unsigned int v = h8[(size_t)s_src[j] * 64 + t];
            auto vl = __builtin_amdgcn_cvt_pk_f32_fp8(v, false);
            auto vh = __builtin_amdgcn_cvt_pk_f32_fp8(v, true);
            a0 += vl[0]; a1 += vl[1]; a2 += vh[0]; a3 += vh[1];
        }
    }
    float4 bb = *(const float4*)(bias + t * 4);
    s4 o;
    o[0] = f2b(fmaxf(fmaf(di, a0, bb.x), 0.f));
    o[1] = f2b(fmaxf(fmaf(di, a1, bb.y), 0.f));
    o[2] = f2b(fmaxf(fmaf(di, a2, bb.z), 0.f));
    o[3] = f2b(fmaxf(fmaf(di, a3, bb.w), 0.f));
    *(s4*)(out + (size_t)i * 256 + t * 4) = o;
}

// ---------------- layer-2 aggregation over bf16 prefolded rows ----------------
// 128 thr/block per dst node; lane t holds features 2t,2t+1
// out = fp32( di * (self + sum_s stored[s]) + b2 )
__global__ __launch_bounds__(128) void k_agg(const __hip_bfloat162* __restrict__ h,
                                             const float* __restrict__ dis,
                                             const int* __restrict__ row_start,
                                             const int* __restrict__ csr,
                                             const float* __restrict__ bias,
                                             float2* __restrict__ out) {
    int i = blockIdx.x;
    int t = threadIdx.x;
    __shared__ int s_src[128];
    float di = dis[i];
    float2 self = __bfloat1622float2(h[(size_t)i * 128 + t]);
    float accx = self.x;
    float accy = self.y;
    int beg = row_start[i], end = row_start[i + 1];
    for (int base = beg; base < end; base += 128) {
        int m = min(128, end - base);
        __syncthreads();
        if (t < m) s_src[t] = csr[base + t];
        __syncthreads();
        for (int j = 0; j < m; ++j) {
            float2 v = __bfloat1622float2(h[(size_t)s_src[j] * 128 + t]);
            accx += v.x;
            accy += v.y;
        }
    }
    const float2* b2 = (const float2*)bias;
    float2 bb = b2[t];
    out[(size_t)i * 128 + t] = make_float2(fmaf(di, accx, bb.x), fmaf(di, accy, bb.y));
}

// ---------------- mean|max readout + final linear (4 chunks/graph, atomic partials) ----------------
__global__ __launch_bounds__(256) void k_readout(const float* __restrict__ h2,
                                                 const float* __restrict__ Wm,
                                                 const float* __restrict__ bm,
                                                 float* __restrict__ out) {
    int g = blockIdx.x, c = blockIdx.y;     // c: feature chunk 0..3
    int t = threadIdx.x;
    int fl = t & 63;                        // feature-in-chunk
    int f  = c * 64 + fl;
    int rs = t >> 6;                        // row subset 0..3 (one per wave)
    const float* base = h2 + (size_t)g * NPG * 256 + f;
    float sum = 0.f, mx = -3.402823466e38f;
    for (int r = rs; r < NPG; r += 4) {
        float v = base[(size_t)r * 256];
        sum += v;
        mx = fmaxf(mx, v);
    }
    __shared__ float s_sum[4][64];
    __shared__ float s_max[4][64];
    s_sum[rs][fl] = sum;
    s_max[rs][fl] = mx;
    __syncthreads();
    if (t < 64) {
        float ts = s_sum[0][t] + s_sum[1][t] + s_sum[2][t] + s_sum[3][t];
        float tm = fmaxf(fmaxf(s_max[0][t], s_max[1][t]), fmaxf(s_max[2][t], s_max[3][t]));
        float mean = ts * (1.0f / NPG);
        float p0 = mean * Wm[f * 2 + 0] + tm * Wm[(256 + f) * 2 + 0];
        float p1 = mean * Wm[f * 2 + 1] + tm * Wm[(256 + f) * 2 + 1];
        for (int o = 32; o > 0; o >>= 1) {
            p0 += __shfl_down(p0, o, 64);
            p1 += __shfl_down(p1, o, 64);
        }
        if (t == 0) {
            if (c == 0) { p0 += bm[0]; p1 += bm[1]; }
            atomicAdd(&out[g * 2 + 0], p0);
            atomicAdd(&out[g * 2 + 1], p1);
        }
    }
}

extern "C" void kernel_launch(void* const* d_in, const int* in_sizes, int n_in,
                              void* d_out, int out_size, void* d_ws, size_t ws_size,
                              hipStream_t stream) {
    const float* x  = (const float*)d_in[0];
    const int*   ei = (const int*)d_in[1];   // int64 in reference -> int32 on device
    // d_in[2] = batch (unused: batch = node/400), d_in[3] = num_graphs (unused)
    const float* W1 = (const float*)d_in[4];
    const float* b1 = (const float*)d_in[5];
    const float* W2 = (const float*)d_in[6];
    const float* b2 = (const float*)d_in[7];
    const float* Wm = (const float*)d_in[8];
    const float* bm = (const float*)d_in[9];
    float* out = (float*)d_out;

    char* ws = (char*)d_ws;
    size_t off = 0;
    auto alloc = [&](size_t bytes) {
        void* p = ws + off;
        off = (off + bytes + 255) & ~(size_t)255;
        return p;
    };
    int*   cnt       = (int*)alloc((size_t)N_NODES * 4);
    int*   part      = (int*)alloc((size_t)N_NODES * 4);
    int*   bsum      = (int*)alloc(512);
    int*   row_start = (int*)alloc((size_t)(N_NODES + 1) * 4);
    float* dis       = (float*)alloc((size_t)N_NODES * 4);
    int*   rank      = (int*)alloc((size_t)E_EDGES * 4);
    int*   csr       = (int*)alloc((size_t)E_EDGES * 4);
    short* Wt1       = (short*)alloc((size_t)256 * 416 * 2);
    short* Wt2       = (short*)alloc((size_t)256 * 256 * 2);
    // Region R1 (52MB): fp8 GEMM1-out (26MB) then reused for bf16 GEMM2-out
    char*  R1        = (char*)alloc((size_t)N_NODES * F1 * 2);
    // Region R2 (105MB): fp32 agg2-out; lower 52MB doubles as bf16 agg1-out
    float* Pf        = (float*)alloc((size_t)N_NODES * F1 * 4);
    unsigned char* P8  = (unsigned char*)R1;   // GEMM1 out: fp8 prefolded
    short*         Pc  = (short*)R1;           // GEMM2 out: bf16 prefolded (after agg1 read of P8)
    short*         Pb  = (short*)Pf;           // agg1 out: bf16 relu'd (dead before agg2 writes Pf)

    hipMemsetAsync(cnt, 0, (size_t)N_NODES * 4, stream);
    hipMemsetAsync(out, 0, (size_t)NUM_G * 2 * 4, stream);
    k_count<<<E_EDGES / 256, 256, 0, stream>>>(ei, cnt, rank);
    k_dis<<<N_NODES / 256, 256, 0, stream>>>(cnt, dis);
    k_scan1<<<N_NODES / 1024, 1024, 0, stream>>>(cnt, part, bsum);
    k_scan2<<<1, 64, 0, stream>>>(bsum);
    k_scan3<<<N_NODES / 1024, 1024, 0, stream>>>(cnt, part, bsum, row_start);
    k_fill<<<E_EDGES / 256, 256, 0, stream>>>(ei, rank, row_start, csr);

    k_cvt_w<<<(256 * 416 + 255) / 256, 256, 0, stream>>>(W1, Wt1, 400, 416);
    k_cvt_w<<<(256 * 256 + 255) / 256, 256, 0, stream>>>(W2, Wt2, 256, 256);

    dim3 gg(N_NODES / 128, 2);
    k_mm<true, 1><<<gg, 256, 0, stream>>>((const void*)x, Wt1, dis, 400, 416, (void*)P8);  // fp8(x@W1 * dis)
    k_agg8<<<N_NODES, 64, 0, stream>>>((const unsigned int*)P8, dis, row_start, csr, b1, Pb); // relu(agg)+b1 -> bf16
    k_mm<false, 2><<<gg, 256, 0, stream>>>((const void*)Pb, Wt2, dis, 256, 256, (void*)Pc);  // bf16(h1@W2 * dis)
    k_agg<<<N_NODES, 128, 0, stream>>>((const __hip_bfloat162*)Pc, dis, row_start, csr, b2,
                                       (float2*)Pf);                                         // agg+b2 -> fp32
    k_readout<<<dim3(NUM_G, 4), 256, 0, stream>>>(Pf, Wm, bm, out);
}

// Round 7
// 784.125 us; speedup vs baseline: 1.4133x; 1.1608x over previous
//
#include <hip/hip_runtime.h>
#include <hip/hip_bf16.h>

#define N_NODES 102400
#define FEAT    400
#define F1      256
#define E_EDGES 4096000
#define NUM_G   256
#define NPG     400

typedef __attribute__((ext_vector_type(8))) short bfrag;   // 8 bf16 (4 VGPR)
typedef __attribute__((ext_vector_type(4))) float ffrag;   // 4 fp32 acc
typedef __attribute__((ext_vector_type(4))) short s4;      // 4 bf16 (8B)

__device__ inline short f2b(float f) {
    __hip_bfloat16 h = __float2bfloat16(f);
    return *reinterpret_cast<short*>(&h);
}
__device__ inline float b2f(short s) {
    unsigned int u = ((unsigned int)(unsigned short)s) << 16;
    return __builtin_bit_cast(float, u);
}

// ---------------- degree count + per-edge rank ----------------
__global__ __launch_bounds__(256) void k_count(const int* __restrict__ ei,
                                               int* __restrict__ cnt,
                                               int* __restrict__ rank) {
    int e = blockIdx.x * 256 + threadIdx.x;
    int d = ei[E_EDGES + e];
    rank[e] = atomicAdd(&cnt[d], 1);
}

__global__ __launch_bounds__(256) void k_dis(const int* __restrict__ cnt,
                                             float* __restrict__ dis) {
    int i = blockIdx.x * 256 + threadIdx.x;
    dis[i] = rsqrtf((float)(cnt[i] + 1));   // +1 self-loop; always > 0
}

// ---------------- prefix sum (3-phase) ----------------
__global__ __launch_bounds__(1024) void k_scan1(const int* __restrict__ cnt,
                                                int* __restrict__ part,
                                                int* __restrict__ bsum) {
    __shared__ int s[1024];
    int t = threadIdx.x, b = blockIdx.x;
    int gid = b * 1024 + t;
    s[t] = cnt[gid];
    __syncthreads();
    for (int off = 1; off < 1024; off <<= 1) {
        int v = (t >= off) ? s[t - off] : 0;
        __syncthreads();
        s[t] += v;
        __syncthreads();
    }
    part[gid] = s[t];            // inclusive
    if (t == 1023) bsum[b] = s[t];
}

__global__ void k_scan2(int* __restrict__ bsum) {
    if (threadIdx.x == 0) {
        int run = 0;
        for (int i = 0; i < N_NODES / 1024; ++i) {
            int v = bsum[i]; bsum[i] = run; run += v;
        }
    }
}

__global__ __launch_bounds__(1024) void k_scan3(const int* __restrict__ cnt,
                                                const int* __restrict__ part,
                                                const int* __restrict__ bsum,
                                                int* __restrict__ row_start) {
    int t = threadIdx.x, b = blockIdx.x;
    int gid = b * 1024 + t;
    int inc = part[gid];
    int ex = inc - cnt[gid] + bsum[b];      // exclusive
    row_start[gid] = ex;
    if (gid == N_NODES - 1) row_start[N_NODES] = inc + bsum[b];
}

// ---------------- CSR fill (no atomics: rank precomputed; plain store) ----------------
__global__ __launch_bounds__(256) void k_fill(const int* __restrict__ ei,
                                              const int* __restrict__ rank,
                                              const int* __restrict__ row_start,
                                              int* __restrict__ csr) {
    int e = blockIdx.x * 256 + threadIdx.x;
    int s = ei[e];
    int d = ei[E_EDGES + e];
    csr[row_start[d] + rank[e]] = s;
}

// ---------------- weight transpose+pad to bf16: Wt[256][Kpad] from W[Kreal][256] ----------------
__global__ __launch_bounds__(256) void k_cvt_w(const float* __restrict__ W,
                                               short* __restrict__ Wt,
                                               int Kreal, int Kpad) {
    int idx = blockIdx.x * 256 + threadIdx.x;
    if (idx >= 256 * Kpad) return;
    int n = idx / Kpad, k = idx - n * Kpad;
    float v = (k < Kreal) ? W[(size_t)k * 256 + n] : 0.f;
    Wt[idx] = f2b(v);
}

// ---------------- bf16 MFMA GEMM: C[M x 256] = fp8( (A[M x K] @ Wt^T) * dis[row] ) ----------------
// 128x128 tile, BK=32, 256 thr = 4 waves (2x2), 64x64 per wave = 4x4 frags 16x16x32
template<bool AF32>
__global__ __launch_bounds__(256) void k_mm(const void* __restrict__ Ap,
                                            const short* __restrict__ Wt, // [256][Kpad] bf16
                                            const float* __restrict__ dis,
                                            int Kreal, int Kpad,
                                            unsigned char* __restrict__ Cp) {
    __shared__ short As[128][40];   // rows m, cols k (pad 40 -> 80B stride, 16B aligned)
    __shared__ short Bs[128][40];   // rows n, cols k
    const int t    = threadIdx.x;
    const int lane = t & 63;
    const int w    = t >> 6;
    const int wm   = w >> 1, wn = w & 1;
    const int m0   = blockIdx.x * 128;
    const int n0   = blockIdx.y * 128;

    const int sr = t >> 1;           // staged row 0..127
    const int sh = (t & 1) * 16;     // k-half 0 / 16

    ffrag acc[4][4];
#pragma unroll
    for (int i = 0; i < 4; ++i)
#pragma unroll
        for (int j = 0; j < 4; ++j) {
            ffrag z = {0.f, 0.f, 0.f, 0.f};
            acc[i][j] = z;
        }

    const int rl = lane & 15;
    const int kc = (lane >> 4) * 8;

    for (int k0 = 0; k0 < Kpad; k0 += 32) {
        short av[16], bv[16];
        if constexpr (AF32) {
            const float* A = (const float*)Ap;
            const float* arow = A + (size_t)(m0 + sr) * Kreal + k0 + sh;
#pragma unroll
            for (int c = 0; c < 4; ++c) {
                float4 v;
                if (k0 + sh + c * 4 < Kreal) v = *(const float4*)(arow + c * 4);
                else                         v = make_float4(0.f, 0.f, 0.f, 0.f);
                av[c * 4 + 0] = f2b(v.x);
                av[c * 4 + 1] = f2b(v.y);
                av[c * 4 + 2] = f2b(v.z);
                av[c * 4 + 3] = f2b(v.w);
            }
        } else {
            const short* A = (const short*)Ap;
            const short* arow = A + (size_t)(m0 + sr) * Kpad + k0 + sh;
            *(bfrag*)&av[0] = *(const bfrag*)arow;
            *(bfrag*)&av[8] = *(const bfrag*)(arow + 8);
        }
        const short* brow = Wt + (size_t)(n0 + sr) * Kpad + k0 + sh;
        *(bfrag*)&bv[0] = *(const bfrag*)brow;
        *(bfrag*)&bv[8] = *(const bfrag*)(brow + 8);

        __syncthreads();
        *(bfrag*)&As[sr][sh]     = *(bfrag*)&av[0];
        *(bfrag*)&As[sr][sh + 8] = *(bfrag*)&av[8];
        *(bfrag*)&Bs[sr][sh]     = *(bfrag*)&bv[0];
        *(bfrag*)&Bs[sr][sh + 8] = *(bfrag*)&bv[8];
        __syncthreads();

        bfrag a[4], b[4];
#pragma unroll
        for (int i = 0; i < 4; ++i) a[i] = *(const bfrag*)&As[wm * 64 + i * 16 + rl][kc];
#pragma unroll
        for (int j = 0; j < 4; ++j) b[j] = *(const bfrag*)&Bs[wn * 64 + j * 16 + rl][kc];
#pragma unroll
        for (int i = 0; i < 4; ++i)
#pragma unroll
            for (int j = 0; j < 4; ++j)
                acc[i][j] = __builtin_amdgcn_mfma_f32_16x16x32_bf16(a[i], b[j], acc[i][j], 0, 0, 0);
    }

    const int rh = lane >> 4;
    float scale[4][4];
#pragma unroll
    for (int i = 0; i < 4; ++i)
#pragma unroll
        for (int q = 0; q < 4; ++q)
            scale[i][q] = dis[m0 + wm * 64 + i * 16 + rh * 4 + q];

#pragma unroll
    for (int i = 0; i < 4; ++i)
#pragma unroll
        for (int j = 0; j < 4; ++j) {
            int col  = n0 + wn * 64 + j * 16 + rl;
            int rowb = m0 + wm * 64 + i * 16 + rh * 4;
#pragma unroll
            for (int q = 0; q < 4; ++q) {
                float v = acc[i][j][q] * scale[i][q];
                int p = __builtin_amdgcn_cvt_pk_fp8_f32(v, 0.f, 0, false);
                Cp[(size_t)(rowb + q) * 256 + col] = (unsigned char)(p & 0xff);
            }
        }
}

// ---------------- aggregation over fp8 prefolded rows ----------------
// 64 thr/block = 1 wave per dst node; lane t holds features 4t..4t+3 (one dword of fp8)
// MODE 0 (layer1): out = bf16( relu( di*(self+sum) + b ) )
// MODE 1 (layer2): out = fp32( di*(self+sum) + b )
template<int MODE>
__global__ __launch_bounds__(64) void k_agg8(const unsigned int* __restrict__ h8, // [N][64] dwords
                                             const float* __restrict__ dis,
                                             const int* __restrict__ row_start,
                                             const int* __restrict__ csr,
                                             const float* __restrict__ bias,
                                             void* __restrict__ outp) {
    const int i = blockIdx.x;
    const int t = threadIdx.x;
    __shared__ int s_src[64];
    float di = dis[i];
    unsigned int u = h8[(size_t)i * 64 + t];
    auto lo = __builtin_amdgcn_cvt_pk_f32_fp8(u, false);
    auto hi = __builtin_amdgcn_cvt_pk_f32_fp8(u, true);
    float a0 = lo[0], a1 = lo[1], a2 = hi[0], a3 = hi[1];

    int beg = row_start[i], end = row_start[i + 1];
    for (int base = beg; base < end; base += 64) {
        int m = min(64, end - base);
        __syncthreads();
        if (t < m) s_src[t] = csr[base + t];
        __syncthreads();
        for (int j = 0; j < m; ++j) {
            unsigned int v = h8[(size_t)s_src[j] * 64 + t];
            auto vl = __builtin_amdgcn_cvt_pk_f32_fp8(v, false);
            auto vh = __builtin_amdgcn_cvt_pk_f32_fp8(v, true);
            a0 += vl[0]; a1 += vl[1]; a2 += vh[0]; a3 += vh[1];
        }
    }
    float4 bb = *(const float4*)(bias + t * 4);
    if constexpr (MODE == 0) {
        s4 o;
        o[0] = f2b(fmaxf(fmaf(di, a0, bb.x), 0.f));
        o[1] = f2b(fmaxf(fmaf(di, a1, bb.y), 0.f));
        o[2] = f2b(fmaxf(fmaf(di, a2, bb.z), 0.f));
        o[3] = f2b(fmaxf(fmaf(di, a3, bb.w), 0.f));
        *(s4*)((short*)outp + (size_t)i * 256 + t * 4) = o;
    } else {
        float4 o = make_float4(fmaf(di, a0, bb.x), fmaf(di, a1, bb.y),
                               fmaf(di, a2, bb.z), fmaf(di, a3, bb.w));
        *(float4*)((float*)outp + (size_t)i * 256 + t * 4) = o;
    }
}

// ---------------- mean|max readout + final linear (4 chunks/graph, atomic partials) ----------------
__global__ __launch_bounds__(256) void k_readout(const float* __restrict__ h2,
                                                 const float* __restrict__ Wm,
                                                 const float* __restrict__ bm,
                                                 float* __restrict__ out) {
    int g = blockIdx.x, c = blockIdx.y;     // c: feature chunk 0..3
    int t = threadIdx.x;
    int fl = t & 63;                        // feature-in-chunk
    int f  = c * 64 + fl;
    int rs = t >> 6;                        // row subset 0..3 (one per wave)
    const float* base = h2 + (size_t)g * NPG * 256 + f;
    float sum = 0.f, mx = -3.402823466e38f;
    for (int r = rs; r < NPG; r += 4) {
        float v = base[(size_t)r * 256];
        sum += v;
        mx = fmaxf(mx, v);
    }
    __shared__ float s_sum[4][64];
    __shared__ float s_max[4][64];
    s_sum[rs][fl] = sum;
    s_max[rs][fl] = mx;
    __syncthreads();
    if (t < 64) {
        float ts = s_sum[0][t] + s_sum[1][t] + s_sum[2][t] + s_sum[3][t];
        float tm = fmaxf(fmaxf(s_max[0][t], s_max[1][t]), fmaxf(s_max[2][t], s_max[3][t]));
        float mean = ts * (1.0f / NPG);
        float p0 = mean * Wm[f * 2 + 0] + tm * Wm[(256 + f) * 2 + 0];
        float p1 = mean * Wm[f * 2 + 1] + tm * Wm[(256 + f) * 2 + 1];
        for (int o = 32; o > 0; o >>= 1) {
            p0 += __shfl_down(p0, o, 64);
            p1 += __shfl_down(p1, o, 64);
        }
        if (t == 0) {
            if (c == 0) { p0 += bm[0]; p1 += bm[1]; }
            atomicAdd(&out[g * 2 + 0], p0);
            atomicAdd(&out[g * 2 + 1], p1);
        }
    }
}

extern "C" void kernel_launch(void* const* d_in, const int* in_sizes, int n_in,
                              void* d_out, int out_size, void* d_ws, size_t ws_size,
                              hipStream_t stream) {
    const float* x  = (const float*)d_in[0];
    const int*   ei = (const int*)d_in[1];   // int64 in reference -> int32 on device
    // d_in[2] = batch (unused: batch = node/400), d_in[3] = num_graphs (unused)
    const float* W1 = (const float*)d_in[4];
    const float* b1 = (const float*)d_in[5];
    const float* W2 = (const float*)d_in[6];
    const float* b2 = (const float*)d_in[7];
    const float* Wm = (const float*)d_in[8];
    const float* bm = (const float*)d_in[9];
    float* out = (float*)d_out;

    char* ws = (char*)d_ws;
    size_t off = 0;
    auto alloc = [&](size_t bytes) {
        void* p = ws + off;
        off = (off + bytes + 255) & ~(size_t)255;
        return p;
    };
    int*   cnt       = (int*)alloc((size_t)N_NODES * 4);
    int*   part      = (int*)alloc((size_t)N_NODES * 4);
    int*   bsum      = (int*)alloc(512);
    int*   row_start = (int*)alloc((size_t)(N_NODES + 1) * 4);
    float* dis       = (float*)alloc((size_t)N_NODES * 4);
    int*   rank      = (int*)alloc((size_t)E_EDGES * 4);
    int*   csr       = (int*)alloc((size_t)E_EDGES * 4);
    short* Wt1       = (short*)alloc((size_t)256 * 416 * 2);
    short* Wt2       = (short*)alloc((size_t)256 * 256 * 2);
    // Region R1 (26MB): fp8 GEMM-out (GEMM1, then reused for GEMM2)
    unsigned char* P8 = (unsigned char*)alloc((size_t)N_NODES * F1);
    // Region R2 (105MB): fp32 agg2-out; lower 52MB doubles as bf16 agg1-out
    float* Pf        = (float*)alloc((size_t)N_NODES * F1 * 4);
    short* Pb        = (short*)Pf;   // agg1 out: bf16 relu'd (dead before agg2 writes Pf)

    hipMemsetAsync(cnt, 0, (size_t)N_NODES * 4, stream);
    hipMemsetAsync(out, 0, (size_t)NUM_G * 2 * 4, stream);
    k_count<<<E_EDGES / 256, 256, 0, stream>>>(ei, cnt, rank);
    k_dis<<<N_NODES / 256, 256, 0, stream>>>(cnt, dis);
    k_scan1<<<N_NODES / 1024, 1024, 0, stream>>>(cnt, part, bsum);
    k_scan2<<<1, 64, 0, stream>>>(bsum);
    k_scan3<<<N_NODES / 1024, 1024, 0, stream>>>(cnt, part, bsum, row_start);
    k_fill<<<E_EDGES / 256, 256, 0, stream>>>(ei, rank, row_start, csr);

    k_cvt_w<<<(256 * 416 + 255) / 256, 256, 0, stream>>>(W1, Wt1, 400, 416);
    k_cvt_w<<<(256 * 256 + 255) / 256, 256, 0, stream>>>(W2, Wt2, 256, 256);

    dim3 gg(N_NODES / 128, 2);
    k_mm<true><<<gg, 256, 0, stream>>>((const void*)x, Wt1, dis, 400, 416, P8);      // fp8(x@W1 * dis)
    k_agg8<0><<<N_NODES, 64, 0, stream>>>((const unsigned int*)P8, dis, row_start,
                                          csr, b1, (void*)Pb);                       // relu(agg)+b1 -> bf16
    k_mm<false><<<gg, 256, 0, stream>>>((const void*)Pb, Wt2, dis, 256, 256, P8);    // fp8(h1@W2 * dis)
    k_agg8<1><<<N_NODES, 64, 0, stream>>>((const unsigned int*)P8, dis, row_start,
                                          csr, b2, (void*)Pf);                       // agg+b2 -> fp32
    k_readout<<<dim3(NUM_G, 4), 256, 0, stream>>>(Pf, Wm, bm, out);
}